// Round 13
// baseline (220.382 us; speedup 1.0000x reference)
//
#include <hip/hip_runtime.h>
#include <hip/hip_bf16.h>
#include <math.h>

// RBF_Conv2d cdist via MFMA implicit GEMM (round 13 = round 12 + LDS-transposed epilogue).
// acc = sum_d A[o][d]*B[d][p] over padded K=80:
//   d<75 : A = bf16(-2*w), B = bf16_rne(x)
//   d=75 : A = wn_hi, B = 1.0   d=76 : A = wn_lo, B = 1.0
//   d=77 : A = 1.0,   B = pn_hi d=78 : A = 1.0,   B = pn_lo
// acc == d2 = pn + wn - 2*dot; epilogue = v_sqrt(max(acc,0)).
// CORRECTNESS RULE: MFMA operands are wave-collective -- builds may be
// lane-divergent, but every MFMA issues after re-convergence.
// Round-13 theory: writes drained at 3.6 of 6.6 TB/s because each strip
// scatters 64x128B lines across 64 planes (page thrash). Stage a row-tile
// (64 planes x 128 cols) in LDS (reusing the dead w-staging buffer), then
// write plane-major float4 runs: 512B contiguous per half-wave per plane.

#define KH 5
#define KW 5
#define PAD 2
#define CH 3
#define DD 75
#define OC 64
#define HH 224
#define WW 224
#define HW (HH * WW)
#define RPB 7            // rows per block (224/32 = 32 chunks per image)
#define TW 128           // LDS tile width (cols); tile B uses 96 of it

using short8_t = __attribute__((ext_vector_type(8))) short;
using f32x16   = __attribute__((ext_vector_type(16))) float;
using f32x4    = __attribute__((ext_vector_type(4))) float;

union Oct { unsigned int w[4]; short8_t v; };

__device__ inline unsigned int rne_bf16(float v) {
    return (unsigned int)__builtin_bit_cast(unsigned short, __float2bfloat16(v));
}

__device__ inline float fsqrt_fast(float x) {
    float r;
    asm("v_sqrt_f32 %0, %1" : "=v"(r) : "v"(x));   // ~1ulp; validated round 10
    return r;
}

// window element value; d is constant after unroll+inline -> all math folds.
template<bool EDGE>
__device__ inline float xelem(const float* __restrict__ xb, int y, int xp, int d) {
    if (d >= DD) return 0.f;
    const int c = d / 25, rem = d % 25, i = rem / 5, j = rem % 5;
    int gy = y + i - PAD;
    int gx = xp + j;
    if constexpr (!EDGE) {
        return xb[(c * HH + gy) * WW + gx];
    } else {
        bool ok = ((unsigned)gy < (unsigned)HH) & ((unsigned)gx < (unsigned)WW);
        int gyc = min(max(gy, 0), HH - 1);
        int gxc = min(max(gx, 0), WW - 1);
        float raw = xb[(c * HH + gyc) * WW + gxc];
        return ok ? raw : 0.f;
    }
}

template<int D0, bool EDGE>
__device__ inline void build_oct_rne(const float* __restrict__ xb, int y, int xp,
                                     float& pn, Oct& b) {
#pragma unroll
    for (int rr = 0; rr < 8; rr += 2) {
        float v0 = xelem<EDGE>(xb, y, xp, D0 + rr);
        float v1 = xelem<EDGE>(xb, y, xp, D0 + rr + 1);
        pn = fmaf(v0, v0, pn);
        pn = fmaf(v1, v1, pn);
        b.w[rr >> 1] = rne_bf16(v0) | (rne_bf16(v1) << 16);
    }
}

// A-octet build from LDS-resident w row; also accumulates this lane's
// partial ||w||^2 over the d's it owns (partner half-wave has the rest).
template<int D0>
__device__ inline void build_aoct_wn(const float* wrow, Oct& a, float& wns) {
#pragma unroll
    for (int rr = 0; rr < 8; rr += 2) {
        float r0 = (D0 + rr     < DD) ? wrow[D0 + rr]     : 0.f;
        float r1 = (D0 + rr + 1 < DD) ? wrow[D0 + rr + 1] : 0.f;
        wns = fmaf(r0, r0, wns);
        wns = fmaf(r1, r1, wns);
        a.w[rr >> 1] = rne_bf16(-2.f * r0) | (rne_bf16(-2.f * r1) << 16);
    }
}

#define MFMA(A, B, C) __builtin_amdgcn_mfma_f32_32x32x16_bf16((A), (B), (C), 0, 0, 0)

// Compute one 32-pixel strip; results go to LDS tile column ctile.
template<bool EDGE>
__device__ inline void do_strip(const float* __restrict__ xb, int y, int xp, int hi,
                                const Oct (&ah)[2][5], float* lds, int ctile) {
    float pnp = 0.f;
    Oct bh[5];
    // builds divergent on hi (compile-time D0 per half-wave)...
    if (hi == 0) {
        build_oct_rne<0,  EDGE>(xb, y, xp, pnp, bh[0]);
        build_oct_rne<16, EDGE>(xb, y, xp, pnp, bh[1]);
        build_oct_rne<32, EDGE>(xb, y, xp, pnp, bh[2]);
        build_oct_rne<48, EDGE>(xb, y, xp, pnp, bh[3]);
        build_oct_rne<64, EDGE>(xb, y, xp, pnp, bh[4]);
    } else {
        build_oct_rne<8,  EDGE>(xb, y, xp, pnp, bh[0]);
        build_oct_rne<24, EDGE>(xb, y, xp, pnp, bh[1]);
        build_oct_rne<40, EDGE>(xb, y, xp, pnp, bh[2]);
        build_oct_rne<56, EDGE>(xb, y, xp, pnp, bh[3]);
        build_oct_rne<72, EDGE>(xb, y, xp, pnp, bh[4]);   // d75..79 -> 0
    }
    float pn = pnp + __shfl_xor(pnp, 32);   // partner half-wave has other d's
    if (hi == 1) {
        // B pad slots (octet d72..79): elem3=1, elem4=1, elem5=pn_hi, elem6=pn_lo
        unsigned int up  = __builtin_bit_cast(unsigned int, pn);
        float pnhv = __builtin_bit_cast(float, up & 0xFFFF0000u);
        unsigned int pnl = rne_bf16(pn - pnhv);
        bh[4].w[1] |= 0x3F800000u;
        bh[4].w[2]  = 0x3F80u | (up & 0xFFFF0000u);
        bh[4].w[3]  = pnl;
    }

    // ...MFMAs only here, fully re-converged.
    f32x16 acc0 = {0.f,0.f,0.f,0.f,0.f,0.f,0.f,0.f,0.f,0.f,0.f,0.f,0.f,0.f,0.f,0.f};
    f32x16 acc1 = acc0;
#pragma unroll
    for (int st = 0; st < 5; ++st) {
        acc0 = MFMA(ah[0][st].v, bh[st].v, acc0);
        acc1 = MFMA(ah[1][st].v, bh[st].v, acc1);
    }

    // C/D: col = lane&31 (pixel), row o = (reg&3)+8*(reg>>2)+4*hi (+32 for acc1).
    // Stage into LDS tile [o][ctile]; half-waves land 2048B apart = same banks,
    // 2-way aliasing (free, m136); 32 lanes write 128B contiguous.
#pragma unroll
    for (int reg = 0; reg < 16; ++reg) {
        int ob = (reg & 3) + 8 * (reg >> 2) + 4 * hi;
        lds[ob * TW + ctile]        = fsqrt_fast(fmaxf(acc0[reg], 0.f));
        lds[(ob + 32) * TW + ctile] = fsqrt_fast(fmaxf(acc1[reg], 0.f));
    }
}

__global__ __launch_bounds__(256, 4) void rbf_mfma(const float* __restrict__ x,
                                                   const float* __restrict__ w,
                                                   float* __restrict__ out) {
    __shared__ float lds[OC * TW];           // 32 KB; w-staging first, tile after
    const int tid  = threadIdx.x;

    // ---- coalesced global->LDS staging of w (once per block) ----
    for (int idx = tid; idx < OC * DD; idx += 256)
        lds[idx] = w[idx];
    __syncthreads();

    const int lane = tid & 63;
    const int l31  = lane & 31;
    const int hi   = lane >> 5;

    // ---- A-fragment + wn build from LDS ----
    float wnp[2] = {0.f, 0.f};
    Oct ah[2][5];
    if (hi == 0) {
#pragma unroll
        for (int mt = 0; mt < 2; ++mt) {
            const float* wrow = lds + (l31 + 32 * mt) * DD;
            build_aoct_wn<0 >(wrow, ah[mt][0], wnp[mt]);
            build_aoct_wn<16>(wrow, ah[mt][1], wnp[mt]);
            build_aoct_wn<32>(wrow, ah[mt][2], wnp[mt]);
            build_aoct_wn<48>(wrow, ah[mt][3], wnp[mt]);
            build_aoct_wn<64>(wrow, ah[mt][4], wnp[mt]);
        }
    } else {
#pragma unroll
        for (int mt = 0; mt < 2; ++mt) {
            const float* wrow = lds + (l31 + 32 * mt) * DD;
            build_aoct_wn<8 >(wrow, ah[mt][0], wnp[mt]);
            build_aoct_wn<24>(wrow, ah[mt][1], wnp[mt]);
            build_aoct_wn<40>(wrow, ah[mt][2], wnp[mt]);
            build_aoct_wn<56>(wrow, ah[mt][3], wnp[mt]);
            build_aoct_wn<72>(wrow, ah[mt][4], wnp[mt]);
        }
    }
    // full ||w||^2 per mt: partner half-wave (same row) holds the other d's
    float wn0 = wnp[0] + __shfl_xor(wnp[0], 32);
    float wn1 = wnp[1] + __shfl_xor(wnp[1], 32);
    if (hi == 1) {
#pragma unroll
        for (int mt = 0; mt < 2; ++mt) {
            // A pad slots: elem3=wn_hi, elem4=wn_lo, elem5=1.0, elem6=1.0, elem7=0
            float wnv = mt ? wn1 : wn0;
            unsigned int uwn = __builtin_bit_cast(unsigned int, wnv);
            float wnhv = __builtin_bit_cast(float, uwn & 0xFFFF0000u);
            unsigned int wnl = rne_bf16(wnv - wnhv);
            ah[mt][4].w[1] = (ah[mt][4].w[1] & 0xFFFFu) | (uwn & 0xFFFF0000u);
            ah[mt][4].w[2] = wnl | (0x3F80u << 16);
            ah[mt][4].w[3] = 0x3F80u;
        }
    }
    __syncthreads();   // w-staging region is dead; lds becomes the out-tile

    // ---- block = 7 contiguous rows of one image ----
    const int b  = blockIdx.x >> 5;
    const int y0 = (blockIdx.x & 31) * RPB;
    const int wv = tid >> 6;
    const float* xb = x + (size_t)b * (CH * HW);
    float* outb = out + (size_t)b * OC * HW;

    const int wp   = tid >> 5;   // 0..7: plane-group index for the write phase
    const int slot = tid & 31;   // float4 slot within a plane row

#pragma unroll 1
    for (int r = 0; r < RPB; ++r) {
        int y = r + y0;
        bool yin = (y >= PAD) & (y < HH - PAD);

        // ---- tile A: strips 0..3 (cols 0..127), wave wv -> strip wv ----
        {
            int sx = wv;
            int xp = sx * 32 + l31 - PAD;
            int ct = sx * 32 + l31;
            if (yin & (sx >= 1)) do_strip<false>(xb, y, xp, hi, ah, lds, ct);
            else                 do_strip<true >(xb, y, xp, hi, ah, lds, ct);
        }
        __syncthreads();
        // write A: per iter, 8 planes; half-wave writes 512B contiguous / plane
        {
            float* orow = outb + (size_t)y * WW + slot * 4;
#pragma unroll
            for (int it = 0; it < 8; ++it) {
                int o = it * 8 + wp;
                f32x4 v = *(const f32x4*)&lds[o * TW + slot * 4];
                *(f32x4*)(orow + (size_t)o * HW) = v;
            }
        }
        __syncthreads();

        // ---- tile B: strips 4..6 (cols 0..95), waves 0..2 ----
        if (wv < 3) {
            int sx = 4 + wv;
            int xp = sx * 32 + l31 - PAD;
            int ct = (sx - 4) * 32 + l31;
            if (yin & (sx <= 5)) do_strip<false>(xb, y, xp, hi, ah, lds, ct);
            else                 do_strip<true >(xb, y, xp, hi, ah, lds, ct);
        }
        __syncthreads();
        // write B: cols 0..95 -> x 128..223 (24 slots of 4 floats per plane)
        if (slot < 24) {
            float* orow = outb + (size_t)y * WW + 128 + slot * 4;
#pragma unroll
            for (int it = 0; it < 8; ++it) {
                int o = it * 8 + wp;
                f32x4 v = *(const f32x4*)&lds[o * TW + slot * 4];
                *(f32x4*)(orow + (size_t)o * HW) = v;
            }
        }
        __syncthreads();
    }
}

extern "C" void kernel_launch(void* const* d_in, const int* in_sizes, int n_in,
                              void* d_out, int out_size, void* d_ws, size_t ws_size,
                              hipStream_t stream) {
    const float* x = (const float*)d_in[0];
    const float* w = (const float*)d_in[1];
    float* out     = (float*)d_out;

    int B       = in_sizes[0] / (CH * HW);   // 32
    int nblocks = B * 32;                    // 32 row-chunks per image, RPB=7

    rbf_mfma<<<nblocks, 256, 0, stream>>>(x, w, out);
}

// Round 14
// 140.792 us; speedup vs baseline: 1.5653x; 1.5653x over previous
//
#include <hip/hip_runtime.h>
#include <hip/hip_bf16.h>
#include <math.h>

// RBF_Conv2d cdist via MFMA implicit GEMM (round 14 = round 12 + o-split occupancy).
// acc = sum_d A[o][d]*B[d][p] over padded K=80:
//   d<75 : A = bf16(-2*w), B = bf16_rne(x)
//   d=75 : A = wn_hi, B = 1.0   d=76 : A = wn_lo, B = 1.0
//   d=77 : A = 1.0,   B = pn_hi d=78 : A = 1.0,   B = pn_lo
// acc == d2 = pn + wn - 2*dot; epilogue = v_sqrt(max(acc,0)).
// CORRECTNESS RULE: MFMA operands are wave-collective -- builds may be
// lane-divergent, but every MFMA issues after re-convergence.
// Round-14: wave = 32 outputs x 32 px (half the o-range of round 12) ->
// acc 16 + ah 20 + bh 20 + misc ~= 90 VGPR -> launch_bounds(256,5) = 5
// waves/SIMD (round 12 was hard-capped at 4 by 128 VGPR). B-builds are
// duplicated across the o-half wave pair; VALU has 10x headroom. Block =
// 4 rows of one image (grid 1792) so 5 blocks/CU are schedulable.
// KNOWN-BAD (collapses VGPR alloc): barriers/LDS indirection around
// do_strip (r13), MFMA in divergent branch (r8), NT stores (r10).

#define KH 5
#define KW 5
#define PAD 2
#define CH 3
#define DD 75
#define OC 64
#define HH 224
#define WW 224
#define HW (HH * WW)
#define NSX 7            // 224/32 strips per row
#define RPB 4            // rows per block (224/4 = 56 chunks per image)

using short8_t = __attribute__((ext_vector_type(8))) short;
using f32x16   = __attribute__((ext_vector_type(16))) float;

union Oct { unsigned int w[4]; short8_t v; };

__device__ inline unsigned int rne_bf16(float v) {
    return (unsigned int)__builtin_bit_cast(unsigned short, __float2bfloat16(v));
}

__device__ inline float fsqrt_fast(float x) {
    float r;
    asm("v_sqrt_f32 %0, %1" : "=v"(r) : "v"(x));   // ~1ulp; validated round 10
    return r;
}

// window element value; d is constant after unroll+inline -> all math folds.
template<bool EDGE>
__device__ inline float xelem(const float* __restrict__ xb, int y, int xp, int d) {
    if (d >= DD) return 0.f;
    const int c = d / 25, rem = d % 25, i = rem / 5, j = rem % 5;
    int gy = y + i - PAD;
    int gx = xp + j;
    if constexpr (!EDGE) {
        return xb[(c * HH + gy) * WW + gx];
    } else {
        bool ok = ((unsigned)gy < (unsigned)HH) & ((unsigned)gx < (unsigned)WW);
        int gyc = min(max(gy, 0), HH - 1);
        int gxc = min(max(gx, 0), WW - 1);
        float raw = xb[(c * HH + gyc) * WW + gxc];
        return ok ? raw : 0.f;
    }
}

template<int D0, bool EDGE>
__device__ inline void build_oct_rne(const float* __restrict__ xb, int y, int xp,
                                     float& pn, Oct& b) {
#pragma unroll
    for (int rr = 0; rr < 8; rr += 2) {
        float v0 = xelem<EDGE>(xb, y, xp, D0 + rr);
        float v1 = xelem<EDGE>(xb, y, xp, D0 + rr + 1);
        pn = fmaf(v0, v0, pn);
        pn = fmaf(v1, v1, pn);
        b.w[rr >> 1] = rne_bf16(v0) | (rne_bf16(v1) << 16);
    }
}

// A-octet build from LDS-resident w row; also accumulates this lane's
// partial ||w||^2 over the d's it owns (partner half-wave has the rest).
template<int D0>
__device__ inline void build_aoct_wn(const float* wrow, Oct& a, float& wns) {
#pragma unroll
    for (int rr = 0; rr < 8; rr += 2) {
        float r0 = (D0 + rr     < DD) ? wrow[D0 + rr]     : 0.f;
        float r1 = (D0 + rr + 1 < DD) ? wrow[D0 + rr + 1] : 0.f;
        wns = fmaf(r0, r0, wns);
        wns = fmaf(r1, r1, wns);
        a.w[rr >> 1] = rne_bf16(-2.f * r0) | (rne_bf16(-2.f * r1) << 16);
    }
}

#define MFMA(A, B, C) __builtin_amdgcn_mfma_f32_32x32x16_bf16((A), (B), (C), 0, 0, 0)

template<bool EDGE>
__device__ inline void do_strip(const float* __restrict__ xb, int y, int xp, int hi,
                                const Oct (&ah)[5], float* __restrict__ op) {
    float pnp = 0.f;
    Oct bh[5];
    // builds divergent on hi (compile-time D0 per half-wave)...
    if (hi == 0) {
        build_oct_rne<0,  EDGE>(xb, y, xp, pnp, bh[0]);
        build_oct_rne<16, EDGE>(xb, y, xp, pnp, bh[1]);
        build_oct_rne<32, EDGE>(xb, y, xp, pnp, bh[2]);
        build_oct_rne<48, EDGE>(xb, y, xp, pnp, bh[3]);
        build_oct_rne<64, EDGE>(xb, y, xp, pnp, bh[4]);
    } else {
        build_oct_rne<8,  EDGE>(xb, y, xp, pnp, bh[0]);
        build_oct_rne<24, EDGE>(xb, y, xp, pnp, bh[1]);
        build_oct_rne<40, EDGE>(xb, y, xp, pnp, bh[2]);
        build_oct_rne<56, EDGE>(xb, y, xp, pnp, bh[3]);
        build_oct_rne<72, EDGE>(xb, y, xp, pnp, bh[4]);   // d75..79 -> 0
    }
    float pn = pnp + __shfl_xor(pnp, 32);   // partner half-wave has other d's
    if (hi == 1) {
        // B pad slots (octet d72..79): elem3=1, elem4=1, elem5=pn_hi, elem6=pn_lo
        unsigned int up  = __builtin_bit_cast(unsigned int, pn);
        float pnhv = __builtin_bit_cast(float, up & 0xFFFF0000u);
        unsigned int pnl = rne_bf16(pn - pnhv);
        bh[4].w[1] |= 0x3F800000u;
        bh[4].w[2]  = 0x3F80u | (up & 0xFFFF0000u);
        bh[4].w[3]  = pnl;
    }

    // ...MFMAs only here, fully re-converged.
    f32x16 acc = {0.f,0.f,0.f,0.f,0.f,0.f,0.f,0.f,0.f,0.f,0.f,0.f,0.f,0.f,0.f,0.f};
#pragma unroll
    for (int st = 0; st < 5; ++st)
        acc = MFMA(ah[st].v, bh[st].v, acc);

    // C/D: col = lane&31, row = (reg&3)+8*(reg>>2)+4*hi; +4*hi folded into op.
#pragma unroll
    for (int reg = 0; reg < 16; ++reg) {
        int ob = (reg & 3) + 8 * (reg >> 2);
        op[(size_t)ob * HW] = fsqrt_fast(fmaxf(acc[reg], 0.f));
    }
}

__global__ __launch_bounds__(256, 5) void rbf_mfma(const float* __restrict__ x,
                                                   const float* __restrict__ w,
                                                   float* __restrict__ out) {
    __shared__ float wlds[OC * DD];          // 19.2 KB
    const int tid  = threadIdx.x;

    // ---- coalesced global->LDS staging of w (once per block) ----
    for (int idx = tid; idx < OC * DD; idx += 256)
        wlds[idx] = w[idx];
    __syncthreads();

    const int lane  = tid & 63;
    const int l31   = lane & 31;
    const int hi    = lane >> 5;
    const int wv    = tid >> 6;
    const int ohalf = wv & 1;    // which 32-plane half this wave owns
    const int sp    = wv >> 1;   // which strip of the pair

    // ---- A-fragment + wn build from LDS (single 32-plane tile) ----
    float wnp = 0.f;
    Oct ah[5];
    const float* wrow = wlds + (l31 + 32 * ohalf) * DD;
    if (hi == 0) {
        build_aoct_wn<0 >(wrow, ah[0], wnp);
        build_aoct_wn<16>(wrow, ah[1], wnp);
        build_aoct_wn<32>(wrow, ah[2], wnp);
        build_aoct_wn<48>(wrow, ah[3], wnp);
        build_aoct_wn<64>(wrow, ah[4], wnp);
    } else {
        build_aoct_wn<8 >(wrow, ah[0], wnp);
        build_aoct_wn<24>(wrow, ah[1], wnp);
        build_aoct_wn<40>(wrow, ah[2], wnp);
        build_aoct_wn<56>(wrow, ah[3], wnp);
        build_aoct_wn<72>(wrow, ah[4], wnp);
    }
    float wn = wnp + __shfl_xor(wnp, 32);    // partner half-wave, same row
    if (hi == 1) {
        // A pad slots: elem3=wn_hi, elem4=wn_lo, elem5=1.0, elem6=1.0, elem7=0
        unsigned int uwn = __builtin_bit_cast(unsigned int, wn);
        float wnhv = __builtin_bit_cast(float, uwn & 0xFFFF0000u);
        unsigned int wnl = rne_bf16(wn - wnhv);
        ah[4].w[1] = (ah[4].w[1] & 0xFFFFu) | (uwn & 0xFFFF0000u);
        ah[4].w[2] = wnl | (0x3F80u << 16);
        ah[4].w[3] = 0x3F80u;
    }

    // ---- strip loop: block = RPB contiguous rows of one image; per iter the
    // 4 waves cover 2 consecutive strips x 2 o-halves (write locality) ----
    const int bi    = blockIdx.x;
    const int b     = bi / 56;               // wave-uniform scalar division
    const int chunk = bi - b * 56;
    const int y0    = chunk * RPB;
    const float* xb = x + (size_t)b * (CH * HW);
    float* outw = out + (size_t)b * OC * HW
                      + (size_t)(ohalf * 32 + hi * 4) * HW + l31;

#pragma unroll 1
    for (int it = 0; it < 2 * NSX; ++it) {   // 28 strips = 14 iters x 2 strips
        int sidx = it * 2 + sp;              // 0..27
        int r    = (sidx * 37) >> 8;         // sidx / 7 (exact for 0..48)
        int sx   = sidx - r * 7;
        int y    = y0 + r;
        int x0   = sx * 32;
        int xp   = x0 + l31 - PAD;
        float* op = outw + (size_t)y * WW + x0;
        bool interior = (y >= PAD) & (y < HH - PAD) & (sx >= 1) & (sx <= 5);
        if (interior) do_strip<false>(xb, y, xp, hi, ah, op);
        else          do_strip<true >(xb, y, xp, hi, ah, op);
    }
}

extern "C" void kernel_launch(void* const* d_in, const int* in_sizes, int n_in,
                              void* d_out, int out_size, void* d_ws, size_t ws_size,
                              hipStream_t stream) {
    const float* x = (const float*)d_in[0];
    const float* w = (const float*)d_in[1];
    float* out     = (float*)d_out;

    int B       = in_sizes[0] / (CH * HW);   // 32
    int nblocks = B * 56;                    // 56 four-row chunks per image

    rbf_mfma<<<nblocks, 256, 0, stream>>>(x, w, out);
}